// Round 5
// baseline (644.647 us; speedup 1.0000x reference)
//
#include <hip/hip_runtime.h>
#include <hip/hip_bf16.h>
#include <math.h>

// Problem: B=64, T=1024, H=1024. M = B*T = 65536 score rows.
// out = [context (64*1024 fp32)] ++ [weights (64*1024 fp32)]
// ws fast path: [scores_p 16x64K f32 = 4MB][dec 256KB][W_bf16 2MB]  (~6.5MB)
// R5: A (spatial) is no longer pre-converted -- enc reg-stages fp32->bf16
// directly (HK-style T14); context reads fp32 spatial. prep = W-cvt + dec only.

typedef __attribute__((ext_vector_type(8))) short bf16x8;
typedef __attribute__((ext_vector_type(8))) unsigned short ushort8;
typedef __attribute__((ext_vector_type(4))) float f32x4;
typedef __attribute__((ext_vector_type(4))) unsigned int u32x4;

__device__ __forceinline__ unsigned short f2bf(float f) {
  union { float f; unsigned int u; } v; v.f = f;
  unsigned int r = v.u + 0x7FFFu + ((v.u >> 16) & 1u);  // RNE
  return (unsigned short)(r >> 16);
}

__device__ __forceinline__ unsigned int pk2bf(float lo, float hi) {
  return (unsigned int)f2bf(lo) | ((unsigned int)f2bf(hi) << 16);
}

__device__ __forceinline__ float fast_tanh(float x) {
  float e = __expf(2.0f * x);
  return 1.0f - 2.0f / (e + 1.0f);  // saturates correctly at +-1
}

// ===== prep kernel: W-cvt (32 blocks) | dec-GEMV (512 blocks) ================
__global__ __launch_bounds__(256) void prep_kernel(
    const float* __restrict__ spatial, const float* __restrict__ hidden,
    const float* __restrict__ W_enc, const float* __restrict__ b_enc,
    const float* __restrict__ W_dec, const float* __restrict__ b_dec,
    unsigned short* __restrict__ Wbf, unsigned short* __restrict__ Abf,
    float* __restrict__ dec, int nCvt) {
  __shared__ float hs[1024];
  const int bid = blockIdx.x, tid = threadIdx.x;
  if (bid < nCvt) {
    // W only: 262144 float4 over 32 blocks x 256 thr x 32 iters
    const float* src = W_enc;
    unsigned short* dst = Wbf;
    const size_t base = (size_t)bid * 8192 + tid;
    #pragma unroll 4
    for (int i = 0; i < 32; i++) {
      size_t g4 = base + (size_t)i * 256;
      float4 v = ((const float4*)src)[g4];
      ushort4 o;
      o.x = f2bf(v.x); o.y = f2bf(v.y); o.z = f2bf(v.z); o.w = f2bf(v.w);
      *(ushort4*)(dst + g4 * 4) = o;
    }
    return;
  }
  const int dbid = bid - nCvt;                // 0..511
  const int b = dbid >> 3, o0 = (dbid & 7) * 128;
  const int wave = tid >> 6, lane = tid & 63;
  ((float4*)hs)[tid] = ((const float4*)(hidden + (size_t)b * 1024))[tid];
  __syncthreads();
  for (int it = 0; it < 32; it++) {
    int o = o0 + it * 4 + wave;
    const float4* w4 = (const float4*)(W_dec + (size_t)o * 1024);
    float4 acc; acc.x = acc.y = acc.z = acc.w = 0.f;
    #pragma unroll
    for (int j = 0; j < 4; j++) {
      int i = j * 64 + lane;
      float4 x = ((const float4*)hs)[i], y = w4[i];
      acc.x = fmaf(x.x, y.x, acc.x);
      acc.y = fmaf(x.y, y.y, acc.y);
      acc.z = fmaf(x.z, y.z, acc.z);
      acc.w = fmaf(x.w, y.w, acc.w);
    }
    float v = (acc.x + acc.y) + (acc.z + acc.w);
    #pragma unroll
    for (int off = 1; off < 64; off <<= 1) v += __shfl_xor(v, off);
    if (lane == 0) dec[b * 1024 + o] = v + b_dec[o] + b_enc[o];
  }
}

// ======== FAST PATH: 256x256 8-phase GEMM, fp32-A reg-staged + cvt ============
// C[m,n] = sum_k A[m,k]*W[n,k], A = fp32 spatial converted in-register.
// Structure = R4's proven 4-phase/K-tile skeleton; staging is now T14
// reg-staging for BOTH operands (no global_load_lds):
//   q0: issue A(kt+1,h0) 4xfloat4 + B(kt+1,h0) 2xuint4  -> regs
//   q1: issue A(kt+1,h1) + B(kt+1,h1)
//   q2: cvt+ds_write h0 -> As/Bs[buf^1]   (compiler inserts the vmcnt wait)
//   q3: cvt+ds_write h1 -> As/Bs[buf^1]
// Publication: writes happen before barrier1 of their phase; the asm
// lgkmcnt(0) after barrier1 drains them in every wave before it can reach
// barrier2 -> all writes globally visible before any kt+1 read. As[buf^1]
// was last READ at kt-1 (two barrier layers earlier) -> no read/write race.
// All global loads are compiler-visible C loads: data-dependence waitcnts
// are compiler-generated (no hand vmcnt ledger). sched_barrier(0) pins the
// issue blocks so loads are not sunk to their use site (rule 18/20).
// T2 swizzle: LDS col slot c holds data col c ^ (row&7) (16B units); write
// slot = ((lane&7)^(lane>>3))*8, read slot = ((s*4+quad)^(colL&7))*8 --
// identical to R4's verified pattern (bank conflicts measured 0).
// T1 XCD swizzle: grid 1024 = 8*128, bijective.
__global__ __launch_bounds__(512, 2) void enc_score_bf16_kernel(
    const float* __restrict__ A,            // fp32 spatial [65536,1024]
    const unsigned short* __restrict__ W,   // bf16 bits [1024,1024]
    const float* __restrict__ dec,          // [64,1024] (b_dec+b_enc folded)
    const float* __restrict__ w_score,
    float* __restrict__ scores_p)           // [16][65536]
{
  __shared__ unsigned short As[2][256][64];   // 64 KB
  __shared__ unsigned short Bs[2][256][64];   // 64 KB

  const int bid = blockIdx.x;                 // 1024 blocks
  const int swz = (bid & 7) * 128 + (bid >> 3);
  const int nt = swz & 3;                     // 4 n-tiles
  const int m0 = (swz >> 2) * 256;
  const int n0 = nt * 256;
  const int tid = threadIdx.x;
  const int lane = tid & 63, wave = tid >> 6; // 8 waves
  const int wm = (wave >> 2) * 128;           // 0 / 128
  const int wn = (wave & 3) * 64;             // 0,64,128,192
  const int quad = lane >> 4, colL = lane & 15;

  // staging rows: wave covers [wave*16 + (lane>>3) + {0,8}] within a half-tile
  const int s_row = wave * 16 + (lane >> 3);
  const int a_col = (lane & 7) * 8;                       // natural col (elems)
  const int w_slot = ((lane & 7) ^ (lane >> 3)) * 8;      // swizzled LDS col
  const float* gA = A + (size_t)m0 * 1024;
  const unsigned short* gB = W + (size_t)n0 * 1024;

  // fragment-read swizzled col slots for kstep s=0,1 (elements)
  const int xs0 = ((0 * 4 + quad) ^ (colL & 7)) * 8;
  const int xs1 = ((1 * 4 + quad) ^ (colL & 7)) * 8;

  float4 rA0[4], rA1[4];   // fp32 staging regs (h0 / h1)
  u32x4  rB0[2], rB1[2];   // bf16 staging regs

  auto issueA = [&](int kt, int h, float4* r) {
    const float* src = gA + (size_t)(h * 128 + s_row) * 1024 + kt * 64 + a_col;
    r[0] = *(const float4*)(src);
    r[1] = *(const float4*)(src + 4);
    r[2] = *(const float4*)(src + 8 * 1024);
    r[3] = *(const float4*)(src + 8 * 1024 + 4);
  };
  auto issueB = [&](int kt, int h, u32x4* r) {
    const unsigned short* src =
        gB + (size_t)(h * 128 + s_row) * 1024 + kt * 64 + a_col;
    r[0] = *(const u32x4*)(src);
    r[1] = *(const u32x4*)(src + 8 * 1024);
  };
  auto writeA = [&](int buf, int h, const float4* r) {
    u32x4 p0, p1;
    p0[0] = pk2bf(r[0].x, r[0].y); p0[1] = pk2bf(r[0].z, r[0].w);
    p0[2] = pk2bf(r[1].x, r[1].y); p0[3] = pk2bf(r[1].z, r[1].w);
    p1[0] = pk2bf(r[2].x, r[2].y); p1[1] = pk2bf(r[2].z, r[2].w);
    p1[2] = pk2bf(r[3].x, r[3].y); p1[3] = pk2bf(r[3].z, r[3].w);
    *(u32x4*)(&As[buf][h * 128 + s_row][w_slot]) = p0;
    *(u32x4*)(&As[buf][h * 128 + s_row + 8][w_slot]) = p1;
  };
  auto writeB = [&](int buf, int h, const u32x4* r) {
    *(u32x4*)(&Bs[buf][h * 128 + s_row][w_slot]) = r[0];
    *(u32x4*)(&Bs[buf][h * 128 + s_row + 8][w_slot]) = r[1];
  };

  f32x4 acc[8][4];
  #pragma unroll
  for (int mi = 0; mi < 8; mi++)
    #pragma unroll
    for (int ni = 0; ni < 4; ni++)
      acc[mi][ni] = (f32x4){0.f, 0.f, 0.f, 0.f};

  // prologue: K-tile 0 staged through regs (one-time latency), publish.
  issueA(0, 0, rA0); issueB(0, 0, rB0);
  issueA(0, 1, rA1); issueB(0, 1, rB1);
  writeA(0, 0, rA0); writeB(0, 0, rB0);
  writeA(0, 1, rA1); writeB(0, 1, rB1);
  asm volatile("s_waitcnt lgkmcnt(0)" ::: "memory");
  __builtin_amdgcn_s_barrier();

  auto ktile = [&](int kt, int buf) {
    bf16x8 bfr[4][2];
    #pragma unroll
    for (int q = 0; q < 4; q++) {
      bf16x8 af[2][2];
      #pragma unroll
      for (int mj = 0; mj < 2; mj++) {
        const int row = wm + (q * 2 + mj) * 16 + colL;
        af[mj][0] = *(const bf16x8*)&As[buf][row][xs0];
        af[mj][1] = *(const bf16x8*)&As[buf][row][xs1];
      }
      if (q == 0) {
        #pragma unroll
        for (int ni = 0; ni < 4; ni++) {
          const int row = wn + ni * 16 + colL;
          bfr[ni][0] = *(const bf16x8*)&Bs[buf][row][xs0];
          bfr[ni][1] = *(const bf16x8*)&Bs[buf][row][xs1];
        }
      }
      if (kt < 15) {
        if (q == 0) { issueA(kt + 1, 0, rA0); issueB(kt + 1, 0, rB0); }
        if (q == 1) { issueA(kt + 1, 1, rA1); issueB(kt + 1, 1, rB1); }
        if (q == 2) { writeA(buf ^ 1, 0, rA0); writeB(buf ^ 1, 0, rB0); }
        if (q == 3) { writeA(buf ^ 1, 1, rA1); writeB(buf ^ 1, 1, rB1); }
      }
      __builtin_amdgcn_sched_barrier(0);
      __builtin_amdgcn_s_barrier();
      asm volatile("s_waitcnt lgkmcnt(0)" ::: "memory");
      __builtin_amdgcn_sched_barrier(0);
      __builtin_amdgcn_s_setprio(1);
      #pragma unroll
      for (int s = 0; s < 2; s++)
        #pragma unroll
        for (int mj = 0; mj < 2; mj++)
          #pragma unroll
          for (int ni = 0; ni < 4; ni++)
            acc[q * 2 + mj][ni] = __builtin_amdgcn_mfma_f32_16x16x32_bf16(
                af[mj][s], bfr[ni][s], acc[q * 2 + mj][ni], 0, 0, 0);
      __builtin_amdgcn_s_setprio(0);
      __builtin_amdgcn_s_barrier();
    }
  };

  for (int ku = 0; ku < 16; ku += 2) {
    ktile(ku, 0);
    ktile(ku + 1, 1);
  }

  // epilogue: tanh(enc + dec') * w_score, reduce over this wave's 64 n's,
  // store into slot (n-tile, wave-n-col) -- non-atomic, all 16 slots written.
  const int b = m0 >> 10;
  float decv[4], wsv[4];
  #pragma unroll
  for (int ni = 0; ni < 4; ni++) {
    int n = n0 + wn + ni * 16 + colL;
    decv[ni] = dec[b * 1024 + n];
    wsv[ni] = w_score[n];
  }
  const int slot = nt * 4 + (wave & 3);
  #pragma unroll
  for (int mi = 0; mi < 8; mi++) {
    float rs[4] = {0.f, 0.f, 0.f, 0.f};
    #pragma unroll
    for (int ni = 0; ni < 4; ni++)
      #pragma unroll
      for (int r = 0; r < 4; r++)
        rs[r] += fast_tanh(acc[mi][ni][r] + decv[ni]) * wsv[ni];
    #pragma unroll
    for (int r = 0; r < 4; r++) {
      float v = rs[r];
      v += __shfl_xor(v, 1);
      v += __shfl_xor(v, 2);
      v += __shfl_xor(v, 4);
      v += __shfl_xor(v, 8);
      if (colL == 0)
        scores_p[slot * 65536 + m0 + wm + mi * 16 + quad * 4 + r] = v;
    }
  }
}

// ======== FALLBACK (ws too small): fused fp32-staging GEMM ====================
__global__ __launch_bounds__(256) void enc_score_f32_kernel(
    const float* __restrict__ A, const float* __restrict__ W,
    const float* __restrict__ dec, const float* __restrict__ w_score,
    float* __restrict__ scores_p) {
  __shared__ unsigned short As[128][32];
  __shared__ unsigned short Bs[128][32];
  const int bid = blockIdx.x;
  const int n0 = (bid & 7) * 128;
  const int m0 = (bid >> 3) * 128;
  const int tid = threadIdx.x;
  const int lane = tid & 63, wave = tid >> 6;
  const int wm = (wave >> 1) * 64, wn = (wave & 1) * 64;
  const int quad = lane >> 4, colL = lane & 15;
  const int srow = tid >> 3;
  const int scol = (tid & 7) * 4;
  f32x4 acc[4][4];
  #pragma unroll
  for (int mi = 0; mi < 4; mi++)
    #pragma unroll
    for (int ni = 0; ni < 4; ni++)
      acc[mi][ni] = (f32x4){0.f, 0.f, 0.f, 0.f};
  for (int k0 = 0; k0 < 1024; k0 += 32) {
    #pragma unroll
    for (int p = 0; p < 4; p++) {
      int r = p * 32 + srow;
      float4 va = *(const float4*)(A + (size_t)(m0 + r) * 1024 + (k0 + scol));
      float4 vb = *(const float4*)(W + (size_t)(n0 + r) * 1024 + (k0 + scol));
      ushort4 pa, pb;
      pa.x = f2bf(va.x); pa.y = f2bf(va.y); pa.z = f2bf(va.z); pa.w = f2bf(va.w);
      pb.x = f2bf(vb.x); pb.y = f2bf(vb.y); pb.z = f2bf(vb.z); pb.w = f2bf(vb.w);
      *(ushort4*)(&As[r][scol]) = pa;
      *(ushort4*)(&Bs[r][scol]) = pb;
    }
    __syncthreads();
    bf16x8 af[4], bfr[4];
    #pragma unroll
    for (int i = 0; i < 4; i++) {
      af[i]  = *(const bf16x8*)(&As[wm + i * 16 + colL][quad * 8]);
      bfr[i] = *(const bf16x8*)(&Bs[wn + i * 16 + colL][quad * 8]);
    }
    #pragma unroll
    for (int mi = 0; mi < 4; mi++)
      #pragma unroll
      for (int ni = 0; ni < 4; ni++)
        acc[mi][ni] = __builtin_amdgcn_mfma_f32_16x16x32_bf16(
            af[mi], bfr[ni], acc[mi][ni], 0, 0, 0);
    __syncthreads();
  }
  const int b = m0 >> 10;
  float decv[4], wsv[4];
  #pragma unroll
  for (int ni = 0; ni < 4; ni++) {
    int n = n0 + wn + ni * 16 + colL;
    decv[ni] = dec[b * 1024 + n];
    wsv[ni] = w_score[n];
  }
  const int slot = (bid & 7) * 2 + (wave & 1);
  #pragma unroll
  for (int mi = 0; mi < 4; mi++) {
    float rsv[4] = {0.f, 0.f, 0.f, 0.f};
    #pragma unroll
    for (int ni = 0; ni < 4; ni++)
      #pragma unroll
      for (int r = 0; r < 4; r++)
        rsv[r] += fast_tanh(acc[mi][ni][r] + decv[ni]) * wsv[ni];
    #pragma unroll
    for (int r = 0; r < 4; r++) {
      float v = rsv[r];
      v += __shfl_xor(v, 1);
      v += __shfl_xor(v, 2);
      v += __shfl_xor(v, 4);
      v += __shfl_xor(v, 8);
      if (colL == 0)
        scores_p[slot * 65536 + m0 + wm + mi * 16 + quad * 4 + r] = v;
    }
  }
}

// ------- softmax over T per batch; sums 16 partial slots; zeros context -------
__global__ void softmax_kernel(const float* __restrict__ scores_p,
                               float* __restrict__ weights,
                               float* __restrict__ context) {
  __shared__ float red[256];
  int b = blockIdx.x, tid = threadIdx.x;
  float4 z; z.x = z.y = z.z = z.w = 0.f;
  ((float4*)context)[blockIdx.x * 256 + tid] = z;
  float v[4];
  float mx = -1e30f;
  #pragma unroll
  for (int i = 0; i < 4; i++) {
    int m = b * 1024 + tid + i * 256;
    float s = 0.f;
    #pragma unroll
    for (int sl = 0; sl < 16; sl++) s += scores_p[sl * 65536 + m];
    v[i] = s;
    mx = fmaxf(mx, v[i]);
  }
  red[tid] = mx; __syncthreads();
  for (int off = 128; off > 0; off >>= 1) {
    if (tid < off) red[tid] = fmaxf(red[tid], red[tid + off]);
    __syncthreads();
  }
  mx = red[0]; __syncthreads();
  float sum = 0.f;
  #pragma unroll
  for (int i = 0; i < 4; i++) { v[i] = __expf(v[i] - mx); sum += v[i]; }
  red[tid] = sum; __syncthreads();
  for (int off = 128; off > 0; off >>= 1) {
    if (tid < off) red[tid] += red[tid + off];
    __syncthreads();
  }
  float inv = 1.0f / red[0];
  #pragma unroll
  for (int i = 0; i < 4; i++) weights[b * 1024 + tid + i * 256] = v[i] * inv;
}

// -------- context[b,h] = sum_t spatial[b,t,h] * weights[b,t]  (fp32) ----------
__global__ void context_f32_kernel(const float* __restrict__ spatial,
                                   const float* __restrict__ weights,
                                   float* __restrict__ context) {
  int b = blockIdx.x >> 3, tq = blockIdx.x & 7;
  int tid = threadIdx.x;
  __shared__ float wl[128];
  if (tid < 128) wl[tid] = weights[b * 1024 + tq * 128 + tid];
  __syncthreads();
  const float4* sp =
      (const float4*)(spatial + ((size_t)(b * 1024 + tq * 128)) * 1024);
  float4 acc; acc.x = acc.y = acc.z = acc.w = 0.f;
  #pragma unroll 4
  for (int t = 0; t < 128; t++) {
    float w = wl[t];
    float4 x = sp[(size_t)t * 256 + tid];
    acc.x = fmaf(w, x.x, acc.x);
    acc.y = fmaf(w, x.y, acc.y);
    acc.z = fmaf(w, x.z, acc.z);
    acc.w = fmaf(w, x.w, acc.w);
  }
  float* c = context + b * 1024 + tid * 4;
  atomicAdd(c + 0, acc.x);
  atomicAdd(c + 1, acc.y);
  atomicAdd(c + 2, acc.z);
  atomicAdd(c + 3, acc.w);
}

extern "C" void kernel_launch(void* const* d_in, const int* in_sizes, int n_in,
                              void* d_out, int out_size, void* d_ws, size_t ws_size,
                              hipStream_t stream) {
  const float* spatial  = (const float*)d_in[0];  // [64,1024,1024]
  const float* hidden   = (const float*)d_in[1];  // [64,1024]
  const float* W_enc    = (const float*)d_in[2];  // [1024,1024]
  const float* b_enc    = (const float*)d_in[3];  // [1024]
  const float* W_dec    = (const float*)d_in[4];  // [1024,1024]
  const float* b_dec    = (const float*)d_in[5];  // [1024]
  const float* w_score  = (const float*)d_in[6];  // [1024]
  // d_in[7] = b_score: softmax shift-invariant, unused.

  float* out      = (float*)d_out;
  float* context  = out;            // 65536 floats
  float* weights  = out + 65536;    // 65536 floats

  float* scores_p = (float*)d_ws;                            // 16*64K f32 @ 0
  float* dec      = scores_p + 16 * 65536;                   // 64K f32 @ 4MB
  unsigned short* Wbf = (unsigned short*)(dec + 65536);      // 1M  @ 4.25MB

  const size_t need = 16ull * 65536 * 4 + 65536 * 4 + 2ull * 1024 * 1024;

  if (ws_size >= need) {
    const int nCvt = 32;   // W-cvt blocks only
    prep_kernel<<<nCvt + 512, 256, 0, stream>>>(
        spatial, hidden, W_enc, b_enc, W_dec, b_dec, Wbf, nullptr, dec, nCvt);
    enc_score_bf16_kernel<<<1024, 512, 0, stream>>>(spatial, Wbf, dec,
                                                    w_score, scores_p);
    softmax_kernel<<<64, 256, 0, stream>>>(scores_p, weights, context);
    context_f32_kernel<<<512, 256, 0, stream>>>(spatial, weights, context);
  } else {
    prep_kernel<<<512, 256, 0, stream>>>(
        spatial, hidden, W_enc, b_enc, W_dec, b_dec, nullptr, nullptr, dec,
        0);
    enc_score_f32_kernel<<<4096, 256, 0, stream>>>(spatial, W_enc, dec,
                                                   w_score, scores_p);
    softmax_kernel<<<64, 256, 0, stream>>>(scores_p, weights, context);
    context_f32_kernel<<<512, 256, 0, stream>>>(spatial, weights, context);
  }
}